// Round 6
// baseline (21.931 us; speedup 1.0000x reference)
//
#include <hip/hip_runtime.h>
#include <math.h>

// MaxYager2d: out[b,f,si,sj] = max(0, 1 - (min_{c,kh,kw} A[b,c,si+kh,sj+kw] + BW[c,kh,kw,f])^(2/3))
// where A = (1-x)^1.5, BW = (1-w)^1.5.  Max over J commutes with the
// monotone-decreasing Yager combine -> tropical min-plus 3x3 conv.
//
// r6: SINGLE dispatch. Each 256-thread block owns (b, row, f-quartet of 8):
// grid 1024 = 4 blocks/CU in independent phases (stage/compute overlap,
// 4-wave barriers). bw slab (8f x 144 taps, f16-packed channel pairs)
// computed per-block into LDS from w (L2-resident) -> no prep kernel, no
// workspace, no s_load stalls; b-taps are wave-uniform ds_reads.
// Inner loop: v_pk_add_f16 + v_pk_min_f16, 2 channels/lane-op (r5-proven,
// absmax 3.9e-3 << 2e-2).

#define CIN  32
#define CP   16   // channel pairs
#define FOUT 32
#define KS   3
#define HW   66   // input spatial
#define SS   64   // output spatial
#define NB   4    // batch
#define LDW  68   // padded LDS row width (67 needed)

typedef _Float16 half2_t __attribute__((ext_vector_type(2)));

static __device__ __forceinline__ half2_t mk2(float a, float b) {
    half2_t r;
    r.x = (_Float16)a;
    r.y = (_Float16)b;
    return r;
}

__global__ __launch_bounds__(256, 4) void yager_minconv(
    const float* __restrict__ x, const float* __restrict__ w,
    float* __restrict__ out)
{
    __shared__ half2_t ldsA[CP][KS][LDW];     // 13 KB: A window, 2 ch per half2
    __shared__ half2_t bws[8][CP][9];         // 4.5 KB: this block's 8 f rows

    const int tid  = threadIdx.x;
    const int fq   = blockIdx.x & 3;          // f-quartet: f in [fq*8, fq*8+8)
    const int rowb = blockIdx.x >> 2;
    const int row  = rowb & (SS - 1);
    const int b    = rowb >> 6;

    // --- stage bw slab: bws[f][cp][t] = (1-w[(c*9+t)*32 + fq*8+f])^1.5 pairs
    for (int i = tid; i < 8 * CP * 9; i += 256) {
        int f  = i / (CP * 9);
        int r  = i - f * (CP * 9);
        int cp = r / 9;
        int t  = r - cp * 9;
        int fg = fq * 8 + f;
        float w0 = w[((2 * cp)     * 9 + t) * FOUT + fg];
        float w1 = w[((2 * cp + 1) * 9 + t) * FOUT + fg];
        float t0 = 1.0f - w0, t1 = 1.0f - w1;
        bws[f][cp][t] = mk2(t0 * sqrtf(t0), t1 * sqrtf(t1));   // t^1.5
    }

    // --- stage A window (3 rows x 32 ch), fusing A = t*sqrt(t)
    for (int i = tid; i < CP * KS * HW; i += 256) {
        int cp  = i / (KS * HW);
        int r   = i - cp * (KS * HW);
        int kr  = r / HW;
        int col = r - kr * HW;
        const float* xp = x + ((size_t)(b * CIN + 2 * cp) * HW + row + kr) * HW + col;
        float t0 = 1.0f - xp[0];
        float t1 = 1.0f - xp[HW * HW];
        ldsA[cp][kr][col] = mk2(t0 * sqrtf(t0), t1 * sqrtf(t1));
    }
    __syncthreads();

    const int lane = tid & 63;                 // output col
    const int wv   = tid >> 6;                 // wave 0..3 -> 2 f each
    const int f0g  = fq * 8 + wv * 2;          // global f of first output

    half2_t M0 = mk2(4.0f, 4.0f);              // > max possible sum (a+b <= 2)
    half2_t M1 = M0;

#pragma unroll 4
    for (int cp = 0; cp < CP; ++cp) {
        half2_t a[KS][KS];
#pragma unroll
        for (int kr = 0; kr < KS; ++kr)
#pragma unroll
            for (int kw = 0; kw < KS; ++kw)
                a[kr][kw] = ldsA[cp][kr][lane + kw];
        const half2_t* __restrict__ b0 = &bws[wv * 2][cp][0];      // wave-uniform
        const half2_t* __restrict__ b1 = &bws[wv * 2 + 1][cp][0];
#pragma unroll
        for (int t = 0; t < 9; ++t) {
            half2_t av = a[t / 3][t % 3];
            M0 = __builtin_elementwise_min(M0, (half2_t)(av + b0[t]));
            M1 = __builtin_elementwise_min(M1, (half2_t)(av + b1[t]));
        }
    }

    float m0 = fminf((float)M0.x, (float)M0.y);
    float m1 = fminf((float)M1.x, (float)M1.y);
    float r0 = 1.0f - exp2f(0.6666666667f * log2f(m0));
    float r1 = 1.0f - exp2f(0.6666666667f * log2f(m1));
    float* op = out + (((size_t)b * FOUT + f0g) * SS + row) * SS + lane;
    op[0]       = fmaxf(r0, 0.0f);
    op[SS * SS] = fmaxf(r1, 0.0f);
}

extern "C" void kernel_launch(void* const* d_in, const int* in_sizes, int n_in,
                              void* d_out, int out_size, void* d_ws, size_t ws_size,
                              hipStream_t stream)
{
    const float* x = (const float*)d_in[0];   // [4,32,66,66] f32
    const float* w = (const float*)d_in[1];   // [288,32] f32
    float* out = (float*)d_out;               // [4,32,64,64] f32
    (void)d_ws; (void)ws_size;

    yager_minconv<<<NB * SS * 4, 256, 0, stream>>>(x, w, out);
}